// Round 4
// baseline (9067.501 us; speedup 1.0000x reference)
//
#include <hip/hip_runtime.h>

// TruncatedHistoryAttn, round 4.
// Phase 1 (unchanged): fp32 tiled GEMM  A = H@W1 (-> ws), B2 = H@W2 (-> d_out).
// Phase 2 (restructured): 8 WGs/batch (64 cols each), 64 W3 floats/thread
//   pinned in registers via ONE asm statement (16 x float4 "+v" operands —
//   round-3's per-element pins let the allocator spill between pins,
//   VGPR_Count=112 proved it). Redundant per-thread softmax (no serial tid==0
//   section), shfl-butterfly cross-k matvec reduction (no pm LDS round-trip),
//   swizzled tilde row for conflict-free ds_read_b128. 4 barriers/step.

#define BB 32
#define SS 512
#define DD 512
#define NS 5
#define KWG 8

#define A_ELEMS    ((size_t)BB * SS * DD)          // 32 MB
#define YBUF_ELEMS ((size_t)2 * BB * DD)           // 128 KB
#define FLAGS_OFF  ((A_ELEMS + YBUF_ELEMS) * 4)
#define FLAGS_BYTES ((size_t)BB * 64 * 4)          // 8 KB (256B line per batch)
#define WS_NEED    (FLAGS_OFF + FLAGS_BYTES)

typedef __attribute__((ext_vector_type(4))) float f32x4;

// ---------------- Phase 1: A = H@W1, B2 = H@W2 (fp32) ----------------
__global__ void __launch_bounds__(256) th_phase1(
    const float* __restrict__ H, const float* __restrict__ W1,
    const float* __restrict__ W2, float* __restrict__ A, float* __restrict__ B2) {
  const int tid = threadIdx.x;
  const int mt = blockIdx.x >> 3;
  const int nt = blockIdx.x & 7;
  const int m0 = mt << 6, n0 = nt << 6;
  __shared__ float Ht[64][20];
  __shared__ float Wt1[16][64];
  __shared__ float Wt2[16][64];
  const int tx = tid & 15, ty = tid >> 4;
  const int sr = tid >> 2, sk = (tid & 3) << 2;
  const int wr = tid >> 4, wn = (tid & 15) << 2;
  float a1[4][4] = {{0.f}}, a2[4][4] = {{0.f}};

  for (int k0 = 0; k0 < DD; k0 += 16) {
    float4 hv  = *(const float4*)&H[(size_t)(m0 + sr) * DD + k0 + sk];
    float4 w1v = *(const float4*)&W1[(size_t)(k0 + wr) * DD + n0 + wn];
    float4 w2v = *(const float4*)&W2[(size_t)(k0 + wr) * DD + n0 + wn];
    *(float4*)&Ht[sr][sk]  = hv;
    *(float4*)&Wt1[wr][wn] = w1v;
    *(float4*)&Wt2[wr][wn] = w2v;
    __syncthreads();
#pragma unroll
    for (int kq = 0; kq < 16; kq += 4) {
      float hs[4][4];
#pragma unroll
      for (int i = 0; i < 4; ++i) {
        float4 h4 = *(const float4*)&Ht[ty * 4 + i][kq];
        hs[i][0] = h4.x; hs[i][1] = h4.y; hs[i][2] = h4.z; hs[i][3] = h4.w;
      }
#pragma unroll
      for (int kk = 0; kk < 4; ++kk) {
        float4 w1f = *(const float4*)&Wt1[kq + kk][tx * 4];
        float4 w2f = *(const float4*)&Wt2[kq + kk][tx * 4];
#pragma unroll
        for (int i = 0; i < 4; ++i) {
          float h = hs[i][kk];
          a1[i][0] = fmaf(h, w1f.x, a1[i][0]);
          a1[i][1] = fmaf(h, w1f.y, a1[i][1]);
          a1[i][2] = fmaf(h, w1f.z, a1[i][2]);
          a1[i][3] = fmaf(h, w1f.w, a1[i][3]);
          a2[i][0] = fmaf(h, w2f.x, a2[i][0]);
          a2[i][1] = fmaf(h, w2f.y, a2[i][1]);
          a2[i][2] = fmaf(h, w2f.z, a2[i][2]);
          a2[i][3] = fmaf(h, w2f.w, a2[i][3]);
        }
      }
    }
    __syncthreads();
  }
#pragma unroll
  for (int i = 0; i < 4; ++i) {
    float4 o1 = make_float4(a1[i][0], a1[i][1], a1[i][2], a1[i][3]);
    float4 o2 = make_float4(a2[i][0], a2[i][1], a2[i][2], a2[i][3]);
    size_t off = (size_t)(m0 + ty * 4 + i) * DD + n0 + tx * 4;
    *(float4*)&A[off]  = o1;
    *(float4*)&B2[off] = o2;
  }
}

// ---------------- Phase 2: the recurrence ----------------
// grid 256 = 8 WGs/batch; bid = g*32+b -> siblings share XCD under mod-8 rr.
__global__ void __launch_bounds__(512) th_phase2(
    const float* __restrict__ H, const float* __restrict__ v,
    const float* __restrict__ W3, const float* __restrict__ A,
    float* __restrict__ Ob,  // d_out: holds B2, overwritten with tilde rows
    float* __restrict__ ybuf, unsigned int* __restrict__ flags) {
  const int tid = threadIdx.x;
  const int b = blockIdx.x & 31;
  const int g = blockIdx.x >> 5;     // 0..7: cols [g*64, g*64+64)
  const int q = tid >> 6;            // wave 0..7
  const int ln = tid & 63;
  const int kc = ln >> 3;            // k-chunk 0..7 (64 k each)
  const int sc8 = ln & 7;            // sub-col 0..7
  const int colW = (g << 6) + (q << 3) + sc8;  // this lane's W3 column

  __shared__ float tlds[8 * 68];     // swizzled tilde row: idx k + 4*(k>>6)
  __shared__ float wred[NS][8];      // per-wave score partials

  // --- W3 slice into registers: w[i] = W3[kc*64+i][colW], i=0..63.
  float wtmp[64];
#pragma unroll
  for (int i = 0; i < 64; ++i)
    wtmp[i] = W3[(size_t)(kc * 64 + i) * DD + colW];
  f32x4 wv[16];
#pragma unroll
  for (int i = 0; i < 16; ++i)
    wv[i] = (f32x4){wtmp[4 * i], wtmp[4 * i + 1], wtmp[4 * i + 2], wtmp[4 * i + 3]};
  // ONE pin: all 64 floats simultaneously live -> allocator must keep them.
  asm volatile("" : "+v"(wv[0]), "+v"(wv[1]), "+v"(wv[2]), "+v"(wv[3]),
                    "+v"(wv[4]), "+v"(wv[5]), "+v"(wv[6]), "+v"(wv[7]),
                    "+v"(wv[8]), "+v"(wv[9]), "+v"(wv[10]), "+v"(wv[11]),
                    "+v"(wv[12]), "+v"(wv[13]), "+v"(wv[14]), "+v"(wv[15]));

  const float v_d = v[tid];
  float aA[NS] = {0.f, 0.f, 0.f, 0.f, 0.f};
  float cC[NS] = {0.f, 0.f, 0.f, 0.f, 0.f};
  float tl[NS] = {0.f, 0.f, 0.f, 0.f, 0.f};
  float tld_prev = 0.f;

  const float* Hb = H + (size_t)b * SS * DD;
  const float* Ab = A + (size_t)b * SS * DD;
  float* Op = Ob + (size_t)b * SS * DD;
  float* yb = ybuf + (size_t)b * DD;     // + slot*BB*DD + d
  unsigned int* fb = flags + b * 64;     // 8 flags, own 256B line

  for (int t5 = 0; t5 < 515; t5 += 5) {
#pragma unroll
    for (int p = 0; p < NS; ++p) {
      const int t = t5 + p;
      if (t < SS) {
        // prefetch (in flight during the poll)
        float h_d = Hb[(size_t)t * DD + tid];
        float bt  = Op[(size_t)t * DD + tid];  // B2[b][t]
        float aNew = 0.f, cNew = 0.f;
        if (t >= 1) {
          aNew = Ab[(size_t)(t - 1) * DD + tid];
          if (tid < 8) {  // lanes 0..7 poll sibling flags in parallel
            while (__hip_atomic_load(&fb[tid], __ATOMIC_RELAXED,
                                     __HIP_MEMORY_SCOPE_AGENT) < (unsigned)t) { }
          }
          __syncthreads();                                   // barrier 1
          __builtin_amdgcn_fence(__ATOMIC_ACQUIRE, "agent");
          cNew = __hip_atomic_load(&yb[(size_t)((t - 1) & 1) * BB * DD + tid],
                                   __ATOMIC_RELAXED, __HIP_MEMORY_SCOPE_AGENT);
          // all siblings passed step t-1 -> B2 row t-1 dead, overwrite w/ out
          if (g == 0) Op[(size_t)(t - 1) * DD + tid] = tld_prev;
        }
        aA[(p + 4) % NS] = aNew;  // entrant s = t-1
        cC[(p + 4) % NS] = cNew;

        // scores: s_j = sum_d tanh(a_j + b_t + c_j) * v_d
        float sj[NS];
#pragma unroll
        for (int j = 0; j < NS; ++j) {
          float x = aA[(p + j) % NS] + bt + cC[(p + j) % NS];
          float e = __expf(2.0f * x);
          sj[j] = (1.0f - 2.0f / (e + 1.0f)) * v_d;
        }
#pragma unroll
        for (int j = 0; j < NS; ++j) {
#pragma unroll
          for (int off = 32; off >= 1; off >>= 1) sj[j] += __shfl_xor(sj[j], off, 64);
        }
        if (ln == 0) {
#pragma unroll
          for (int j = 0; j < NS; ++j) wred[j][q] = sj[j];
        }
        __syncthreads();                                     // barrier 2

        // redundant per-thread softmax (no serial section, no broadcast LDS)
        float sc[NS];
#pragma unroll
        for (int j = 0; j < NS; ++j) {
          f32x4 r0 = *(const f32x4*)&wred[j][0];
          f32x4 r1 = *(const f32x4*)&wred[j][4];
          sc[j] = ((r0.x + r0.y) + (r0.z + r0.w)) + ((r1.x + r1.y) + (r1.z + r1.w));
        }
        float mx = sc[0];
#pragma unroll
        for (int j = 1; j < NS; ++j) mx = fmaxf(mx, sc[j]);
        float es = 0.f;
        float wsm[NS];
#pragma unroll
        for (int j = 0; j < NS; ++j) { wsm[j] = __expf(sc[j] - mx); es += wsm[j]; }
        float inv = 1.0f / es;

        float hh = 0.f;
#pragma unroll
        for (int j = 0; j < NS; ++j) hh = fmaf(wsm[j] * inv, tl[(p + j) % NS], hh);
        float tld = h_d + fmaxf(hh, 0.f);
        tl[p] = tld;  // entrant s = t (old slot held s = t-5, consumed above)
        tlds[tid + 4 * (tid >> 6)] = tld;  // swizzled store
        __syncthreads();                                     // barrier 3

        // matvec slice: col colW, k in [kc*64, kc*64+64); conflict-free b128
        const f32x4* tv = (const f32x4*)tlds + kc * 17;
        float q0 = 0.f, q1 = 0.f, q2 = 0.f, q3 = 0.f;
#pragma unroll
        for (int i = 0; i < 16; ++i) {
          f32x4 t4 = tv[i];
          q0 = fmaf(t4.x, wv[i].x, q0);
          q1 = fmaf(t4.y, wv[i].y, q1);
          q2 = fmaf(t4.z, wv[i].z, q2);
          q3 = fmaf(t4.w, wv[i].w, q3);
        }
        float cs = (q0 + q1) + (q2 + q3);
        // cross-k butterfly: lanes sharing sc8 (xor 8,16,32) sum to full k
        cs += __shfl_xor(cs, 8, 64);
        cs += __shfl_xor(cs, 16, 64);
        cs += __shfl_xor(cs, 32, 64);
        if (ln < 8) {  // lane ln holds col (g<<6)+(q<<3)+ln
          __hip_atomic_store(&yb[(size_t)(t & 1) * BB * DD + colW], cs,
                             __ATOMIC_RELAXED, __HIP_MEMORY_SCOPE_AGENT);
        }
        __syncthreads();                                     // barrier 4
        if (tid == 0)
          __hip_atomic_store(&fb[g], (unsigned)(t + 1), __ATOMIC_RELEASE,
                             __HIP_MEMORY_SCOPE_AGENT);
        tld_prev = tld;
      }
    }
  }
  if (g == 0) Op[(size_t)(SS - 1) * DD + tid] = tld_prev;
}

extern "C" void kernel_launch(void* const* d_in, const int* in_sizes, int n_in,
                              void* d_out, int out_size, void* d_ws, size_t ws_size,
                              hipStream_t stream) {
  const float* H  = (const float*)d_in[0];
  const float* v  = (const float*)d_in[1];
  const float* W1 = (const float*)d_in[2];
  const float* W2 = (const float*)d_in[3];
  const float* W3 = (const float*)d_in[4];
  float* out = (float*)d_out;

  if (ws_size < WS_NEED) return;

  float* A    = (float*)d_ws;
  float* ybuf = A + A_ELEMS;
  unsigned int* flags = (unsigned int*)((char*)d_ws + FLAGS_OFF);

  (void)hipMemsetAsync(flags, 0, FLAGS_BYTES, stream);
  hipLaunchKernelGGL(th_phase1, dim3(256 * 8), dim3(256), 0, stream,
                     H, W1, W2, A, out);
  hipLaunchKernelGGL(th_phase2, dim3(BB * KWG), dim3(512), 0, stream,
                     H, v, W3, A, out, ybuf, flags);
}

// Round 5
// 2020.140 us; speedup vs baseline: 4.4886x; 4.4886x over previous
//
#include <hip/hip_runtime.h>

// TruncatedHistoryAttn, round 5.
// Phase 1 (unchanged): fp32 tiled GEMM  A = H@W1 (-> ws), B2 = H@W2 (-> d_out).
// Phase 2 = round-3 structure (4 WGs/batch) with two fixes:
//   (a) NO per-step cache-maintenance: acquire fence and release store removed.
//       Rounds 1/3/4 show time scales with WGsPerBatch x fenceCount: agent
//       acquire = buffer_inv (L1+L2 invalidate) every step killed all L2
//       locality. Correctness without fences: __syncthreads drains vmcnt(0)
//       (data stores acked) before the relaxed flag store; consumer ybuf
//       atomic loads can't issue before the post-poll barrier releases.
//   (b) W3 in AGPRs via explicit v_accvgpr_write/read asm (volatile). VGPR
//       pins failed twice (alloc spills after the pin point); AGPRs have no
//       competing pressure.

#define BB 32
#define SS 512
#define DD 512
#define NS 5

#define A_ELEMS    ((size_t)BB * SS * DD)          // 32 MB
#define YBUF_ELEMS ((size_t)2 * BB * DD)           // 128 KB
#define FLAGS_OFF  ((A_ELEMS + YBUF_ELEMS) * 4)
#define FLAGS_BYTES ((size_t)BB * 64 * 4)          // 8 KB (256B line per batch)
#define WS_NEED    (FLAGS_OFF + FLAGS_BYTES)

typedef __attribute__((ext_vector_type(4))) float f32x4;

// ---------------- Phase 1: A = H@W1, B2 = H@W2 (fp32) ----------------
__global__ void __launch_bounds__(256) th_phase1(
    const float* __restrict__ H, const float* __restrict__ W1,
    const float* __restrict__ W2, float* __restrict__ A, float* __restrict__ B2) {
  const int tid = threadIdx.x;
  const int mt = blockIdx.x >> 3;
  const int nt = blockIdx.x & 7;
  const int m0 = mt << 6, n0 = nt << 6;
  __shared__ float Ht[64][20];
  __shared__ float Wt1[16][64];
  __shared__ float Wt2[16][64];
  const int tx = tid & 15, ty = tid >> 4;
  const int sr = tid >> 2, sk = (tid & 3) << 2;
  const int wr = tid >> 4, wn = (tid & 15) << 2;
  float a1[4][4] = {{0.f}}, a2[4][4] = {{0.f}};

  for (int k0 = 0; k0 < DD; k0 += 16) {
    float4 hv  = *(const float4*)&H[(size_t)(m0 + sr) * DD + k0 + sk];
    float4 w1v = *(const float4*)&W1[(size_t)(k0 + wr) * DD + n0 + wn];
    float4 w2v = *(const float4*)&W2[(size_t)(k0 + wr) * DD + n0 + wn];
    *(float4*)&Ht[sr][sk]  = hv;
    *(float4*)&Wt1[wr][wn] = w1v;
    *(float4*)&Wt2[wr][wn] = w2v;
    __syncthreads();
#pragma unroll
    for (int kq = 0; kq < 16; kq += 4) {
      float hs[4][4];
#pragma unroll
      for (int i = 0; i < 4; ++i) {
        float4 h4 = *(const float4*)&Ht[ty * 4 + i][kq];
        hs[i][0] = h4.x; hs[i][1] = h4.y; hs[i][2] = h4.z; hs[i][3] = h4.w;
      }
#pragma unroll
      for (int kk = 0; kk < 4; ++kk) {
        float4 w1f = *(const float4*)&Wt1[kq + kk][tx * 4];
        float4 w2f = *(const float4*)&Wt2[kq + kk][tx * 4];
#pragma unroll
        for (int i = 0; i < 4; ++i) {
          float h = hs[i][kk];
          a1[i][0] = fmaf(h, w1f.x, a1[i][0]);
          a1[i][1] = fmaf(h, w1f.y, a1[i][1]);
          a1[i][2] = fmaf(h, w1f.z, a1[i][2]);
          a1[i][3] = fmaf(h, w1f.w, a1[i][3]);
          a2[i][0] = fmaf(h, w2f.x, a2[i][0]);
          a2[i][1] = fmaf(h, w2f.y, a2[i][1]);
          a2[i][2] = fmaf(h, w2f.z, a2[i][2]);
          a2[i][3] = fmaf(h, w2f.w, a2[i][3]);
        }
      }
    }
    __syncthreads();
  }
#pragma unroll
  for (int i = 0; i < 4; ++i) {
    float4 o1 = make_float4(a1[i][0], a1[i][1], a1[i][2], a1[i][3]);
    float4 o2 = make_float4(a2[i][0], a2[i][1], a2[i][2], a2[i][3]);
    size_t off = (size_t)(m0 + ty * 4 + i) * DD + n0 + tx * 4;
    *(float4*)&A[off]  = o1;
    *(float4*)&B2[off] = o2;
  }
}

// ---------------- Phase 2: the recurrence ----------------
// grid 128 = 4 WGs/batch; bid = g*32+b -> siblings share an XCD (mod-8 rr).
__global__ void __launch_bounds__(512, 1) th_phase2(
    const float* __restrict__ H, const float* __restrict__ v,
    const float* __restrict__ W3, const float* __restrict__ A,
    float* __restrict__ Ob,  // d_out: holds B2, overwritten with tilde rows
    float* __restrict__ ybuf, unsigned int* __restrict__ flags) {
  const int tid = threadIdx.x;
  const int b = blockIdx.x & 31;
  const int g = blockIdx.x >> 5;     // 0..3: cols [g*128, g*128+128)
  const int q = tid >> 6;            // wave 0..7
  const int ln = tid & 63;
  const int seg = tid >> 7;          // k-quarter 0..3 (128 k each)
  const int cc  = tid & 127;         // column within WG slice
  const int col = (g << 7) + cc;

  __shared__ float tlds[DD];         // tilde_t row
  __shared__ float pm[DD];           // matvec partials [seg*128 + cc]
  __shared__ float wred[NS][8];      // per-wave score partials

  // ---- W3 slice into AGPRs: wa[i] = W3[seg*128+i][col], i = 0..127.
  float wa[128];
#pragma unroll
  for (int i = 0; i < 128; ++i) {
    float t = W3[(size_t)(seg * 128 + i) * DD + col];
    asm volatile("v_accvgpr_write_b32 %0, %1" : "=a"(wa[i]) : "v"(t));
  }

  const float v_d = v[tid];
  float aA[NS] = {0.f, 0.f, 0.f, 0.f, 0.f};
  float cC[NS] = {0.f, 0.f, 0.f, 0.f, 0.f};
  float tl[NS] = {0.f, 0.f, 0.f, 0.f, 0.f};
  float tld_prev = 0.f;

  const float* Hb = H + (size_t)b * SS * DD;
  const float* Ab = A + (size_t)b * SS * DD;
  float* Op = Ob + (size_t)b * SS * DD;
  float* yb = ybuf + (size_t)b * DD;     // + slot*BB*DD + d
  unsigned int* fb = flags + b * 64;     // 4 flags, own 256B line

  for (int t5 = 0; t5 < 515; t5 += 5) {
#pragma unroll
    for (int p = 0; p < NS; ++p) {
      const int t = t5 + p;
      if (t < SS) {
        // prefetch (in flight during the poll)
        float h_d = Hb[(size_t)t * DD + tid];
        float bt  = Op[(size_t)t * DD + tid];  // B2[b][t]
        float aNew = 0.f, cNew = 0.f;
        if (t >= 1) {
          aNew = Ab[(size_t)(t - 1) * DD + tid];
          if (tid < 4) {  // lanes 0..3 poll sibling flags in parallel
            while (__hip_atomic_load(&fb[tid], __ATOMIC_RELAXED,
                                     __HIP_MEMORY_SCOPE_AGENT) < (unsigned)t) { }
          }
          __syncthreads();                                   // barrier 1
          // no fence: ybuf loads are agent atomics issued after the barrier;
          // producer's stores were vmcnt-drained before its (relaxed) flag.
          cNew = __hip_atomic_load(&yb[(size_t)((t - 1) & 1) * BB * DD + tid],
                                   __ATOMIC_RELAXED, __HIP_MEMORY_SCOPE_AGENT);
          // all siblings passed step t-1 -> B2 row t-1 dead, overwrite w/ out
          if (g == 0) Op[(size_t)(t - 1) * DD + tid] = tld_prev;
        }
        aA[(p + 4) % NS] = aNew;  // entrant s = t-1
        cC[(p + 4) % NS] = cNew;

        // scores: s_j = sum_d tanh(a_j + b_t + c_j) * v_d
        float sj[NS];
#pragma unroll
        for (int j = 0; j < NS; ++j) {
          float x = aA[(p + j) % NS] + bt + cC[(p + j) % NS];
          float e = __expf(2.0f * x);
          sj[j] = (1.0f - 2.0f / (e + 1.0f)) * v_d;
        }
#pragma unroll
        for (int j = 0; j < NS; ++j) {
#pragma unroll
          for (int off = 32; off >= 1; off >>= 1) sj[j] += __shfl_xor(sj[j], off, 64);
        }
        if (ln == 0) {
#pragma unroll
          for (int j = 0; j < NS; ++j) wred[j][q] = sj[j];
        }
        __syncthreads();                                     // barrier 2

        // redundant per-thread softmax (no serial section)
        float sc[NS];
#pragma unroll
        for (int j = 0; j < NS; ++j) {
          f32x4 r0 = *(const f32x4*)&wred[j][0];
          f32x4 r1 = *(const f32x4*)&wred[j][4];
          sc[j] = ((r0.x + r0.y) + (r0.z + r0.w)) + ((r1.x + r1.y) + (r1.z + r1.w));
        }
        float mx = sc[0];
#pragma unroll
        for (int j = 1; j < NS; ++j) mx = fmaxf(mx, sc[j]);
        float es = 0.f;
        float wsm[NS];
#pragma unroll
        for (int j = 0; j < NS; ++j) { wsm[j] = __expf(sc[j] - mx); es += wsm[j]; }
        float inv = 1.0f / es;

        float hh = 0.f;
#pragma unroll
        for (int j = 0; j < NS; ++j) hh = fmaf(wsm[j] * inv, tl[(p + j) % NS], hh);
        float tld = h_d + fmaxf(hh, 0.f);
        tl[p] = tld;  // entrant s = t (old slot held s = t-5, consumed above)
        tlds[tid] = tld;
        __syncthreads();                                     // barrier 3

        // matvec: col `col`, k in [seg*128, seg*128+128). tlds reads are
        // wave-uniform (broadcast, conflict-free); weights from AGPRs.
        float q0 = 0.f, q1 = 0.f, q2 = 0.f, q3 = 0.f;
        const f32x4* tv = (const f32x4*)&tlds[seg << 7];
#pragma unroll
        for (int i = 0; i < 32; ++i) {
          f32x4 t4 = tv[i];
          float w0, w1, w2, w3;
          asm volatile("v_accvgpr_read_b32 %0, %1" : "=v"(w0) : "a"(wa[4 * i + 0]));
          asm volatile("v_accvgpr_read_b32 %0, %1" : "=v"(w1) : "a"(wa[4 * i + 1]));
          asm volatile("v_accvgpr_read_b32 %0, %1" : "=v"(w2) : "a"(wa[4 * i + 2]));
          asm volatile("v_accvgpr_read_b32 %0, %1" : "=v"(w3) : "a"(wa[4 * i + 3]));
          q0 = fmaf(t4.x, w0, q0);
          q1 = fmaf(t4.y, w1, q1);
          q2 = fmaf(t4.z, w2, q2);
          q3 = fmaf(t4.w, w3, q3);
        }
        pm[tid] = (q0 + q1) + (q2 + q3);
        __syncthreads();                                     // barrier 4
        if (tid < 128) {
          float cs = pm[cc] + pm[128 + cc] + pm[256 + cc] + pm[384 + cc];
          __hip_atomic_store(&yb[(size_t)(t & 1) * BB * DD + col], cs,
                             __ATOMIC_RELAXED, __HIP_MEMORY_SCOPE_AGENT);
        }
        __syncthreads();  // barrier 5: drains vmcnt -> stores acked
        if (tid == 0)
          __hip_atomic_store(&fb[g], (unsigned)(t + 1), __ATOMIC_RELAXED,
                             __HIP_MEMORY_SCOPE_AGENT);
        tld_prev = tld;
      }
    }
  }
  if (g == 0) Op[(size_t)(SS - 1) * DD + tid] = tld_prev;
}

extern "C" void kernel_launch(void* const* d_in, const int* in_sizes, int n_in,
                              void* d_out, int out_size, void* d_ws, size_t ws_size,
                              hipStream_t stream) {
  const float* H  = (const float*)d_in[0];
  const float* v  = (const float*)d_in[1];
  const float* W1 = (const float*)d_in[2];
  const float* W2 = (const float*)d_in[3];
  const float* W3 = (const float*)d_in[4];
  float* out = (float*)d_out;

  if (ws_size < WS_NEED) return;

  float* A    = (float*)d_ws;
  float* ybuf = A + A_ELEMS;
  unsigned int* flags = (unsigned int*)((char*)d_ws + FLAGS_OFF);

  (void)hipMemsetAsync(flags, 0, FLAGS_BYTES, stream);
  hipLaunchKernelGGL(th_phase1, dim3(256 * 8), dim3(256), 0, stream,
                     H, W1, W2, A, out);
  hipLaunchKernelGGL(th_phase2, dim3(BB * 4), dim3(512), 0, stream,
                     H, v, W3, A, out, ybuf, flags);
}

// Round 6
// 1752.283 us; speedup vs baseline: 5.1747x; 1.1529x over previous
//
#include <hip/hip_runtime.h>

// TruncatedHistoryAttn, round 6.
// Phase 1 (unchanged): fp32 tiled GEMM  A = H@W1 (-> ws), B2 = H@W2 (-> d_out).
// Phase 2 changes vs round 5 (no fences, AGPR-resident W3 — both kept):
//  - 8 WGs/batch (grid 256, all CUs; 64 cols/WG, 64 AGPR weights/thread):
//    matvec VALU halves (round-4's 8-WG regression was the fences, now gone).
//  - software pipeline: h/bt/A-row for step t+1 prefetched during step t
//    (global latency off the critical path).
//  - pre-poll scores: j=0..3 depend only on ring regs + bt -> computed before
//    the sync; only j=4 (needs cNew) is post-barrier.
//  - barrier-5 removed: ybuf stores are all wave-0's own; s_waitcnt vmcnt(0)
//    in wave 0 orders them before the relaxed flag store.

#define BB 32
#define SS 512
#define DD 512
#define NS 5
#define KWG 8

#define A_ELEMS    ((size_t)BB * SS * DD)          // 32 MB
#define YBUF_ELEMS ((size_t)2 * BB * DD)           // 128 KB
#define FLAGS_OFF  ((A_ELEMS + YBUF_ELEMS) * 4)
#define FLAGS_BYTES ((size_t)BB * 64 * 4)          // 8 KB (256B line per batch)
#define WS_NEED    (FLAGS_OFF + FLAGS_BYTES)

typedef __attribute__((ext_vector_type(4))) float f32x4;

// ---------------- Phase 1: A = H@W1, B2 = H@W2 (fp32) ----------------
__global__ void __launch_bounds__(256) th_phase1(
    const float* __restrict__ H, const float* __restrict__ W1,
    const float* __restrict__ W2, float* __restrict__ A, float* __restrict__ B2) {
  const int tid = threadIdx.x;
  const int mt = blockIdx.x >> 3;
  const int nt = blockIdx.x & 7;
  const int m0 = mt << 6, n0 = nt << 6;
  __shared__ float Ht[64][20];
  __shared__ float Wt1[16][64];
  __shared__ float Wt2[16][64];
  const int tx = tid & 15, ty = tid >> 4;
  const int sr = tid >> 2, sk = (tid & 3) << 2;
  const int wr = tid >> 4, wn = (tid & 15) << 2;
  float a1[4][4] = {{0.f}}, a2[4][4] = {{0.f}};

  for (int k0 = 0; k0 < DD; k0 += 16) {
    float4 hv  = *(const float4*)&H[(size_t)(m0 + sr) * DD + k0 + sk];
    float4 w1v = *(const float4*)&W1[(size_t)(k0 + wr) * DD + n0 + wn];
    float4 w2v = *(const float4*)&W2[(size_t)(k0 + wr) * DD + n0 + wn];
    *(float4*)&Ht[sr][sk]  = hv;
    *(float4*)&Wt1[wr][wn] = w1v;
    *(float4*)&Wt2[wr][wn] = w2v;
    __syncthreads();
#pragma unroll
    for (int kq = 0; kq < 16; kq += 4) {
      float hs[4][4];
#pragma unroll
      for (int i = 0; i < 4; ++i) {
        float4 h4 = *(const float4*)&Ht[ty * 4 + i][kq];
        hs[i][0] = h4.x; hs[i][1] = h4.y; hs[i][2] = h4.z; hs[i][3] = h4.w;
      }
#pragma unroll
      for (int kk = 0; kk < 4; ++kk) {
        float4 w1f = *(const float4*)&Wt1[kq + kk][tx * 4];
        float4 w2f = *(const float4*)&Wt2[kq + kk][tx * 4];
#pragma unroll
        for (int i = 0; i < 4; ++i) {
          float h = hs[i][kk];
          a1[i][0] = fmaf(h, w1f.x, a1[i][0]);
          a1[i][1] = fmaf(h, w1f.y, a1[i][1]);
          a1[i][2] = fmaf(h, w1f.z, a1[i][2]);
          a1[i][3] = fmaf(h, w1f.w, a1[i][3]);
          a2[i][0] = fmaf(h, w2f.x, a2[i][0]);
          a2[i][1] = fmaf(h, w2f.y, a2[i][1]);
          a2[i][2] = fmaf(h, w2f.z, a2[i][2]);
          a2[i][3] = fmaf(h, w2f.w, a2[i][3]);
        }
      }
    }
    __syncthreads();
  }
#pragma unroll
  for (int i = 0; i < 4; ++i) {
    float4 o1 = make_float4(a1[i][0], a1[i][1], a1[i][2], a1[i][3]);
    float4 o2 = make_float4(a2[i][0], a2[i][1], a2[i][2], a2[i][3]);
    size_t off = (size_t)(m0 + ty * 4 + i) * DD + n0 + tx * 4;
    *(float4*)&A[off]  = o1;
    *(float4*)&B2[off] = o2;
  }
}

// ---------------- Phase 2: the recurrence ----------------
// grid 256 = 8 WGs/batch; bid = g*32+b -> all siblings on one XCD (mod-8 rr).
__global__ void __launch_bounds__(512) th_phase2(
    const float* __restrict__ H, const float* __restrict__ v,
    const float* __restrict__ W3, const float* __restrict__ A,
    float* __restrict__ Ob,  // d_out: holds B2, overwritten with tilde rows
    float* __restrict__ ybuf, unsigned int* __restrict__ flags) {
  const int tid = threadIdx.x;
  const int b = blockIdx.x & 31;
  const int g = blockIdx.x >> 5;     // 0..7: cols [g*64, g*64+64)
  const int q = tid >> 6;            // wave id == k-segment 0..7 (64 k each)
  const int ln = tid & 63;           // column within WG slice
  const int col = (g << 6) + ln;

  __shared__ float tlds[DD];         // tilde_t row
  __shared__ float pm[DD];           // matvec partials [q*64 + ln]
  __shared__ float wred[NS][8];      // per-wave score partials

  // ---- W3 slice into AGPRs: wa[i] = W3[q*64+i][col], i = 0..63.
  float wa[64];
#pragma unroll
  for (int i = 0; i < 64; ++i) {
    float t = W3[(size_t)(q * 64 + i) * DD + col];
    asm volatile("v_accvgpr_write_b32 %0, %1" : "=a"(wa[i]) : "v"(t));
  }

  const float v_d = v[tid];
  float aA[NS] = {0.f, 0.f, 0.f, 0.f, 0.f};
  float cC[NS] = {0.f, 0.f, 0.f, 0.f, 0.f};
  float tl[NS] = {0.f, 0.f, 0.f, 0.f, 0.f};
  float tld_prev = 0.f;

  const float* Hb = H + (size_t)b * SS * DD;
  const float* Ab = A + (size_t)b * SS * DD;
  float* Op = Ob + (size_t)b * SS * DD;
  float* yb = ybuf + (size_t)b * DD;     // + slot*BB*DD + d
  unsigned int* fb = flags + b * 64;     // 8 flags, own 256B line

  // pipeline registers: values for the CURRENT step, loaded one step early
  float h_cur  = Hb[tid];
  float bt_cur = Op[tid];   // B2[b][0]
  float aN_cur = 0.f;       // entrant A-row for t=0 is zeros (s = -1)

  for (int t5 = 0; t5 < 515; t5 += 5) {
#pragma unroll
    for (int p = 0; p < NS; ++p) {
      const int t = t5 + p;
      if (t < SS) {
        // ---- prefetch step t+1 (latency hidden behind this whole step)
        float h_nxt = 0.f, bt_nxt = 0.f, aN_nxt = 0.f;
        if (t + 1 < SS) {
          h_nxt  = Hb[(size_t)(t + 1) * DD + tid];
          bt_nxt = Op[(size_t)(t + 1) * DD + tid];
          aN_nxt = Ab[(size_t)t * DD + tid];  // A row t = entrant for step t+1
        }

        // ---- pre-poll scores j=0..3 (only ring regs + bt_cur needed)
        float sj[NS];
#pragma unroll
        for (int j = 0; j < 4; ++j) {
          float x = aA[(p + j) % NS] + bt_cur + cC[(p + j) % NS];
          float e = __expf(2.0f * x);
          sj[j] = (1.0f - 2.0f / (e + 1.0f)) * v_d;
        }
#pragma unroll
        for (int j = 0; j < 4; ++j) {
#pragma unroll
          for (int off = 32; off >= 1; off >>= 1) sj[j] += __shfl_xor(sj[j], off, 64);
        }
        if (ln == 0) {
#pragma unroll
          for (int j = 0; j < 4; ++j) wred[j][q] = sj[j];
        }

        // ---- sync with siblings; fetch entrant c = tilde_{t-1} @ W3
        float cNew = 0.f;
        if (t >= 1) {
          if (tid < KWG) {
            while (__hip_atomic_load(&fb[tid], __ATOMIC_RELAXED,
                                     __HIP_MEMORY_SCOPE_AGENT) < (unsigned)t) { }
          }
          __syncthreads();                                   // barrier 1
          cNew = __hip_atomic_load(&yb[(size_t)((t - 1) & 1) * BB * DD + tid],
                                   __ATOMIC_RELAXED, __HIP_MEMORY_SCOPE_AGENT);
          // all siblings passed t-1 -> B2 row t-1 dead, overwrite with output
          if (g == 0) Op[(size_t)(t - 1) * DD + tid] = tld_prev;
        }
        aA[(p + 4) % NS] = aN_cur;  // entrant s = t-1
        cC[(p + 4) % NS] = cNew;

        // ---- score j=4 (the only post-sync one)
        {
          float x = aN_cur + bt_cur + cNew;
          float e = __expf(2.0f * x);
          float s4 = (1.0f - 2.0f / (e + 1.0f)) * v_d;
#pragma unroll
          for (int off = 32; off >= 1; off >>= 1) s4 += __shfl_xor(s4, off, 64);
          if (ln == 0) wred[4][q] = s4;
        }
        __syncthreads();                                     // barrier 2

        // ---- redundant per-thread softmax
        float sc[NS];
#pragma unroll
        for (int j = 0; j < NS; ++j) {
          f32x4 r0 = *(const f32x4*)&wred[j][0];
          f32x4 r1 = *(const f32x4*)&wred[j][4];
          sc[j] = ((r0.x + r0.y) + (r0.z + r0.w)) + ((r1.x + r1.y) + (r1.z + r1.w));
        }
        float mx = sc[0];
#pragma unroll
        for (int j = 1; j < NS; ++j) mx = fmaxf(mx, sc[j]);
        float es = 0.f;
        float wsm[NS];
#pragma unroll
        for (int j = 0; j < NS; ++j) { wsm[j] = __expf(sc[j] - mx); es += wsm[j]; }
        float inv = 1.0f / es;

        float hh = 0.f;
#pragma unroll
        for (int j = 0; j < NS; ++j) hh = fmaf(wsm[j] * inv, tl[(p + j) % NS], hh);
        float tld = h_cur + fmaxf(hh, 0.f);
        tl[p] = tld;  // entrant s = t (old slot held s = t-5, consumed above)
        tlds[tid] = tld;
        __syncthreads();                                     // barrier 3

        // ---- matvec: col `col`, k in [q*64, q*64+64); wave-uniform LDS reads
        float q0 = 0.f, q1 = 0.f, q2 = 0.f, q3 = 0.f;
        const f32x4* tv = (const f32x4*)&tlds[q << 6];
#pragma unroll
        for (int i = 0; i < 16; ++i) {
          f32x4 t4 = tv[i];
          float w0, w1, w2, w3;
          asm volatile("v_accvgpr_read_b32 %0, %1" : "=v"(w0) : "a"(wa[4 * i + 0]));
          asm volatile("v_accvgpr_read_b32 %0, %1" : "=v"(w1) : "a"(wa[4 * i + 1]));
          asm volatile("v_accvgpr_read_b32 %0, %1" : "=v"(w2) : "a"(wa[4 * i + 2]));
          asm volatile("v_accvgpr_read_b32 %0, %1" : "=v"(w3) : "a"(wa[4 * i + 3]));
          q0 = fmaf(t4.x, w0, q0);
          q1 = fmaf(t4.y, w1, q1);
          q2 = fmaf(t4.z, w2, q2);
          q3 = fmaf(t4.w, w3, q3);
        }
        pm[tid] = (q0 + q1) + (q2 + q3);
        __syncthreads();                                     // barrier 4
        // cross-segment reduce + publish: all in wave 0 -> no extra barrier;
        // s_waitcnt vmcnt(0) orders ybuf stores before the relaxed flag.
        if (tid < 64) {
          float cs = 0.f;
#pragma unroll
          for (int s = 0; s < 8; ++s) cs += pm[s * 64 + tid];
          __hip_atomic_store(&yb[(size_t)(t & 1) * BB * DD + (g << 6) + tid], cs,
                             __ATOMIC_RELAXED, __HIP_MEMORY_SCOPE_AGENT);
        }
        if (tid == 0) {
          asm volatile("s_waitcnt vmcnt(0)" ::: "memory");
          __hip_atomic_store(&fb[g], (unsigned)(t + 1), __ATOMIC_RELAXED,
                             __HIP_MEMORY_SCOPE_AGENT);
        }
        tld_prev = tld;
        h_cur = h_nxt; bt_cur = bt_nxt; aN_cur = aN_nxt;
      }
    }
  }
  if (g == 0) Op[(size_t)(SS - 1) * DD + tid] = tld_prev;
}

extern "C" void kernel_launch(void* const* d_in, const int* in_sizes, int n_in,
                              void* d_out, int out_size, void* d_ws, size_t ws_size,
                              hipStream_t stream) {
  const float* H  = (const float*)d_in[0];
  const float* v  = (const float*)d_in[1];
  const float* W1 = (const float*)d_in[2];
  const float* W2 = (const float*)d_in[3];
  const float* W3 = (const float*)d_in[4];
  float* out = (float*)d_out;

  if (ws_size < WS_NEED) return;

  float* A    = (float*)d_ws;
  float* ybuf = A + A_ELEMS;
  unsigned int* flags = (unsigned int*)((char*)d_ws + FLAGS_OFF);

  (void)hipMemsetAsync(flags, 0, FLAGS_BYTES, stream);
  hipLaunchKernelGGL(th_phase1, dim3(256 * 8), dim3(256), 0, stream,
                     H, W1, W2, A, out);
  hipLaunchKernelGGL(th_phase2, dim3(BB * KWG), dim3(512), 0, stream,
                     H, v, W3, A, out, ybuf, flags);
}